// Round 3
// baseline (1277.654 us; speedup 1.0000x reference)
//
#include <hip/hip_runtime.h>

#define N_NODES 86016
#define N_EDGES 4194304
#define HID 32
#define B_GR 1024
#define NPG 84
#define NEG 0.2f
#define BSH 4                       // 16 nodes per bucket
#define NBUCK (N_NODES >> BSH)      // 5376 buckets
#define BCAP 2048                   // LDS record capacity per bucket (mean 780, 45-sigma headroom)

// ---- workspace layout (bytes) ----
// Edge record: float4 {src(int), ea.x, ea.y, dst(int)} — built in-place in two phases.
constexpr size_t O_REC  = 0;                                   // E * 16 B
constexpr size_t O_HT   = O_REC + (size_t)N_EDGES * 16;        // N*32 f32
constexpr size_t O_HB   = O_HT  + (size_t)N_NODES * HID * 4;   // N*32 f32
constexpr size_t O_AS   = O_HB  + (size_t)N_NODES * HID * 4;   // N f32
constexpr size_t O_AD   = O_AS  + (size_t)N_NODES * 4;         // N f32
constexpr size_t O_DEG  = O_AD  + (size_t)N_NODES * 4;         // N int
constexpr size_t O_FILL = O_DEG + (size_t)N_NODES * 4;         // N int (bucket cursors use first NBUCK)
constexpr size_t O_ROW  = O_FILL + (size_t)N_NODES * 4;        // N+1 int
constexpr size_t O_BSUM = O_ROW + (size_t)(N_NODES + 1) * 4 + 12; // 84 int (16B aligned)
constexpr size_t O_BOFF = O_BSUM + 84 * 4;                     // 84 int
constexpr size_t O_FOLD = O_BOFF + 84 * 4;                     // 8 f32

__global__ void k_zero(int* __restrict__ p, int n) {
    int i = blockIdx.x * blockDim.x + threadIdx.x;
    if (i < n) p[i] = 0;
}

__global__ void k_count(const int* __restrict__ dst, int* __restrict__ deg) {
    int stride = gridDim.x * blockDim.x;
    for (int e = blockIdx.x * blockDim.x + threadIdx.x; e < N_EDGES; e += stride)
        atomicAdd(&deg[dst[e]], 1);
}

__global__ void k_scanA(const int* __restrict__ deg, int* __restrict__ row, int* __restrict__ bsum) {
    __shared__ int s[1024];
    int t = threadIdx.x;
    int gi = blockIdx.x * 1024 + t;
    s[t] = deg[gi];
    __syncthreads();
    for (int off = 1; off < 1024; off <<= 1) {
        int x = (t >= off) ? s[t - off] : 0;
        __syncthreads();
        s[t] += x;
        __syncthreads();
    }
    row[gi + 1] = s[t];
    if (t == 1023) bsum[blockIdx.x] = s[t];
}

__global__ void k_scanB(const int* __restrict__ bsum, int* __restrict__ boff) {
    __shared__ int s[84];
    int t = threadIdx.x;
    if (t < 84) s[t] = bsum[t];
    __syncthreads();
    if (t == 0) {
        int r = 0;
        for (int b = 0; b < 84; ++b) { int v = s[b]; s[b] = r; r += v; }
    }
    __syncthreads();
    if (t < 84) boff[t] = s[t];
}

__global__ void k_scanC(int* __restrict__ row, const int* __restrict__ boff) {
    int t = threadIdx.x;
    int gi = blockIdx.x * 1024 + t;
    row[gi + 1] += boff[blockIdx.x];
    if (gi == 0) row[0] = 0;
}

// Phase 2: append each edge to its dst-bucket's region of the FINAL rec array
// (region = [row[b*16], row[(b+1)*16])). 5376 active cursors -> ~672 KB write
// window, L2-resident, full lines before eviction.
__global__ void k_scatter2(const int* __restrict__ ei, const float2* __restrict__ ea,
                           const int* __restrict__ row, int* __restrict__ bfill,
                           float4* __restrict__ rec) {
    int stride = gridDim.x * blockDim.x;
    for (int e = blockIdx.x * blockDim.x + threadIdx.x; e < N_EDGES; e += stride) {
        int s = ei[e];
        int d = ei[N_EDGES + e];
        float2 a = ea[e];
        int b = d >> BSH;
        int pos = row[b << BSH] + atomicAdd(&bfill[b], 1);
        float4 r;
        r.x = __int_as_float(s);
        r.y = a.x;
        r.z = a.y;
        r.w = __int_as_float(d);
        rec[pos] = r;
    }
}

// Phase 3: per-bucket in-place sort to exact per-node CSR order via LDS.
__global__ __launch_bounds__(256) void k_sortbucket(float4* __restrict__ rec,
                                                    const int* __restrict__ row) {
    __shared__ float4 lrec[BCAP];
    __shared__ int lfill[1 << BSH];
    int b = blockIdx.x;
    int t = threadIdx.x;
    int n0 = b << BSH;
    int beg = row[n0], end = row[n0 + (1 << BSH)];
    int cnt = end - beg;
    if (t < (1 << BSH)) lfill[t] = 0;
    int m = cnt < BCAP ? cnt : BCAP;
    for (int i = t; i < m; i += 256) lrec[i] = rec[beg + i];
    // statistically unreachable overflow path (keeps correctness airtight)
    float4 ov[4]; int novf = 0;
    for (int i = BCAP + t; i < cnt; i += 256)
        if (novf < 4) ov[novf++] = rec[beg + i];
    __syncthreads();
    for (int i = t; i < m; i += 256) {
        float4 r = lrec[i];
        int d = __float_as_int(r.w);
        int pos = row[d] + atomicAdd(&lfill[d - n0], 1);
        rec[pos] = r;
    }
    for (int k = 0; k < novf; ++k) {
        float4 r = ov[k];
        int d = __float_as_int(r.w);
        int pos = row[d] + atomicAdd(&lfill[d - n0], 1);
        rec[pos] = r;
    }
}

// fold[l*2+c] = sum_j We[l][c][j] * att_edge[l][j]
__global__ void k_fold(const float* __restrict__ We, const float* __restrict__ ae,
                       float* __restrict__ fold) {
    int t = threadIdx.x;
    if (t < 8) {
        int l = t >> 1, c = t & 1;
        float s = 0.f;
        for (int j = 0; j < 32; ++j) s += We[l * 64 + c * 32 + j] * ae[l * 32 + j];
        fold[t] = s;
    }
}

__global__ void k_transform0(const float* __restrict__ x, const float* __restrict__ W0,
                             const float* __restrict__ as_w, const float* __restrict__ ad_w,
                             float* __restrict__ hout, float* __restrict__ as_arr,
                             float* __restrict__ ad_arr) {
    int tid = blockIdx.x * 256 + threadIdx.x;
    int j = tid & 31;
    int n = tid >> 5;
    float acc = x[n] * W0[j];
    hout[tid] = acc;
    float v1 = acc * as_w[j], v2 = acc * ad_w[j];
#pragma unroll
    for (int m = 16; m >= 1; m >>= 1) {
        v1 += __shfl_xor(v1, m);
        v2 += __shfl_xor(v2, m);
    }
    if (j == 0) { as_arr[n] = v1; ad_arr[n] = v2; }
}

__global__ void k_transform(const float* __restrict__ hin, const float* __restrict__ W,
                            const float* __restrict__ as_w, const float* __restrict__ ad_w,
                            float* __restrict__ hout, float* __restrict__ as_arr,
                            float* __restrict__ ad_arr) {
    __shared__ float Wl[1024];
    int t = threadIdx.x;
#pragma unroll
    for (int i = 0; i < 4; ++i) Wl[t + i * 256] = W[t + i * 256];
    __syncthreads();
    int tid = blockIdx.x * 256 + t;
    int j = tid & 31;
    int n = tid >> 5;
    float hv = hin[tid];
    float acc = 0.f;
#pragma unroll
    for (int k = 0; k < 32; ++k) acc += __shfl(hv, k, 32) * Wl[k * 32 + j];
    hout[tid] = acc;
    float v1 = acc * as_w[j], v2 = acc * ad_w[j];
#pragma unroll
    for (int m = 16; m >= 1; m >>= 1) {
        v1 += __shfl_xor(v1, m);
        v2 += __shfl_xor(v2, m);
    }
    if (j == 0) { as_arr[n] = v1; ad_arr[n] = v2; }
}

// one wave per node; lane&31 = feature dim; half-waves take alternating edges;
// 4-deep unroll => 8 edge records + 8 hT lines in flight per wave (latency hiding).
__global__ void k_gather(const float* __restrict__ hT, const float4* __restrict__ rec,
                         const int* __restrict__ row,
                         const float* __restrict__ as_arr, const float* __restrict__ ad_arr,
                         const float* __restrict__ fold, const float* __restrict__ bias,
                         float* __restrict__ out, int do_relu) {
    int lane = threadIdx.x & 63;
    int n = blockIdx.x * 4 + (threadIdx.x >> 6);
    int j = lane & 31;
    int half = lane >> 5;
    int beg = row[n], end = row[n + 1];
    float c_dst = ad_arr[n];
    float f0 = fold[0], f1 = fold[1];
    float acc = 0.f, den = 0.f, esum = 0.f;
    int e = beg + half;
    for (; e + 6 < end; e += 8) {
        float4 r0 = rec[e];
        float4 r1 = rec[e + 2];
        float4 r2 = rec[e + 4];
        float4 r3 = rec[e + 6];
        int s0 = __float_as_int(r0.x);
        int s1 = __float_as_int(r1.x);
        int s2 = __float_as_int(r2.x);
        int s3 = __float_as_int(r3.x);
        float h0 = hT[(s0 << 5) + j];
        float h1 = hT[(s1 << 5) + j];
        float h2 = hT[(s2 << 5) + j];
        float h3 = hT[(s3 << 5) + j];
        float a0 = as_arr[s0];
        float a1 = as_arr[s1];
        float a2 = as_arr[s2];
        float a3 = as_arr[s3];
        float ed0 = r0.y * f0 + r0.z * f1;
        float ed1 = r1.y * f0 + r1.z * f1;
        float ed2 = r2.y * f0 + r2.z * f1;
        float ed3 = r3.y * f0 + r3.z * f1;
        float lg0 = a0 + c_dst + ed0; lg0 = fmaxf(lg0, NEG * lg0);
        float lg1 = a1 + c_dst + ed1; lg1 = fmaxf(lg1, NEG * lg1);
        float lg2 = a2 + c_dst + ed2; lg2 = fmaxf(lg2, NEG * lg2);
        float lg3 = a3 + c_dst + ed3; lg3 = fmaxf(lg3, NEG * lg3);
        float w0 = __expf(lg0);
        float w1 = __expf(lg1);
        float w2 = __expf(lg2);
        float w3 = __expf(lg3);
        den += (w0 + w1) + (w2 + w3);
        esum += (ed0 + ed1) + (ed2 + ed3);
        acc += w0 * h0;
        acc += w1 * h1;
        acc += w2 * h2;
        acc += w3 * h3;
    }
    for (; e < end; e += 2) {
        float4 r = rec[e];
        int s = __float_as_int(r.x);
        float h = hT[(s << 5) + j];
        float ed = r.y * f0 + r.z * f1;
        float lg = as_arr[s] + c_dst + ed;
        lg = fmaxf(lg, NEG * lg);
        float w = __expf(lg);
        den += w;
        esum += ed;
        acc += w * h;
    }
    acc += __shfl_xor(acc, 32);
    den += __shfl_xor(den, 32);
    esum += __shfl_xor(esum, 32);
    // self loop: edge attr = mean of incoming (0 if deg==0), src = n
    int dg = end - beg;
    float el = esum / fmaxf((float)dg, 1.0f);
    float lg = as_arr[n] + c_dst + el;
    lg = fmaxf(lg, NEG * lg);
    float w = __expf(lg);
    den += w;
    acc += w * hT[(n << 5) + j];
    float o = acc / den + bias[j];
    if (do_relu) o = fmaxf(o, 0.f);
    if (half == 0) out[(n << 5) + j] = o;
}

__global__ void k_pool(const float* __restrict__ h, const float* __restrict__ lw,
                       const float* __restrict__ lb, float* __restrict__ out) {
    int lane = threadIdx.x & 63;
    int g = blockIdx.x * 4 + (threadIdx.x >> 6);
    int j = lane & 31;
    int half = lane >> 5;
    const float* base = h + (size_t)g * NPG * HID;
    float acc = 0.f;
    for (int i = half; i < NPG; i += 2) acc += base[i * HID + j];
    acc += __shfl_xor(acc, 32);
    float v = acc * lw[j];
#pragma unroll
    for (int m = 16; m >= 1; m >>= 1) v += __shfl_xor(v, m);
    if (lane == 0) out[g] = fmaxf(v + lb[0], 0.f);
}

extern "C" void kernel_launch(void* const* d_in, const int* in_sizes, int n_in,
                              void* d_out, int out_size, void* d_ws, size_t ws_size,
                              hipStream_t stream) {
    const float* x        = (const float*)d_in[0];
    const int*   ei       = (const int*)d_in[1];
    const float* eattr    = (const float*)d_in[2];
    const float* W0       = (const float*)d_in[3];
    const float* Ws       = (const float*)d_in[4];
    const float* att_src  = (const float*)d_in[5];
    const float* att_dst  = (const float*)d_in[6];
    const float* We       = (const float*)d_in[7];
    const float* att_edge = (const float*)d_in[8];
    const float* bias     = (const float*)d_in[9];
    const float* lin_w    = (const float*)d_in[10];
    const float* lin_b    = (const float*)d_in[11];
    float* out = (float*)d_out;

    char* w = (char*)d_ws;
    float4* rec      = (float4*)(w + O_REC);
    float*  hT       = (float*)(w + O_HT);
    float*  hB       = (float*)(w + O_HB);
    float*  as_arr   = (float*)(w + O_AS);
    float*  ad_arr   = (float*)(w + O_AD);
    int*    deg      = (int*)(w + O_DEG);
    int*    row      = (int*)(w + O_ROW);
    int*    fill     = (int*)(w + O_FILL);
    int*    bsum     = (int*)(w + O_BSUM);
    int*    boff     = (int*)(w + O_BOFF);
    float*  fold     = (float*)(w + O_FOLD);

    // ---- build CSR by dst, two-phase bucketed ----
    k_zero<<<(2 * N_NODES + 255) / 256, 256, 0, stream>>>(deg, 2 * N_NODES);
    k_count<<<4096, 256, 0, stream>>>(ei + N_EDGES, deg);
    k_scanA<<<84, 1024, 0, stream>>>(deg, row, bsum);
    k_scanB<<<1, 128, 0, stream>>>(bsum, boff);
    k_scanC<<<84, 1024, 0, stream>>>(row, boff);
    k_scatter2<<<8192, 256, 0, stream>>>(ei, (const float2*)eattr, row, fill, rec);
    k_sortbucket<<<NBUCK, 256, 0, stream>>>(rec, row);
    k_fold<<<1, 64, 0, stream>>>(We, att_edge, fold);

    // ---- layer 0 ----
    k_transform0<<<N_NODES * HID / 256, 256, 0, stream>>>(x, W0, att_src, att_dst,
                                                          hT, as_arr, ad_arr);
    k_gather<<<N_NODES / 4, 256, 0, stream>>>(hT, rec, row, as_arr, ad_arr,
                                              fold, bias, hB, 1);
    // ---- layers 1..3 ----
    for (int l = 1; l < 4; ++l) {
        k_transform<<<N_NODES * HID / 256, 256, 0, stream>>>(
            hB, Ws + (size_t)(l - 1) * HID * HID, att_src + l * HID, att_dst + l * HID,
            hT, as_arr, ad_arr);
        k_gather<<<N_NODES / 4, 256, 0, stream>>>(hT, rec, row, as_arr, ad_arr,
                                                  fold + 2 * l, bias + l * HID, hB,
                                                  (l < 3) ? 1 : 0);
    }

    // ---- pool + linear + relu ----
    k_pool<<<B_GR / 4, 256, 0, stream>>>(hB, lin_w, lin_b, out);
}

// Round 5
// 1185.516 us; speedup vs baseline: 1.0777x; 1.0777x over previous
//
#include <hip/hip_runtime.h>

#define N_NODES 86016
#define N_EDGES 4194304
#define HID 32
#define B_GR 1024
#define NPG 84
#define NEG 0.2f

typedef float nfloat4 __attribute__((ext_vector_type(4)));  // NT-load-compatible

// ---- workspace layout (bytes) ----
// Edge record: float4 {src(int), ea.x, ea.y, unused}
constexpr size_t O_REC  = 0;                                   // E * 16 B
constexpr size_t O_HT   = O_REC + (size_t)N_EDGES * 16;        // N*32 bf16 (2 B)
constexpr size_t O_HB   = O_HT  + (size_t)N_NODES * HID * 2;   // N*32 f32
constexpr size_t O_AS   = O_HB  + (size_t)N_NODES * HID * 4;   // N f32
constexpr size_t O_AD   = O_AS  + (size_t)N_NODES * 4;         // N f32
constexpr size_t O_DEG  = O_AD  + (size_t)N_NODES * 4;         // N int
constexpr size_t O_FILL = O_DEG + (size_t)N_NODES * 4;         // N int
constexpr size_t O_ROW  = O_FILL + (size_t)N_NODES * 4;        // N+1 int
constexpr size_t O_BSUM = O_ROW + (size_t)(N_NODES + 1) * 4 + 12; // 84 int (16B aligned)
constexpr size_t O_BOFF = O_BSUM + 84 * 4;                     // 84 int
constexpr size_t O_FOLD = O_BOFF + 84 * 4;                     // 8 f32

__device__ __forceinline__ unsigned short f2bf(float f) {
    unsigned u = __float_as_uint(f);
    u += 0x7FFFu + ((u >> 16) & 1u);      // round-to-nearest-even
    return (unsigned short)(u >> 16);
}
__device__ __forceinline__ float bf2f(unsigned short b) {
    return __uint_as_float(((unsigned)b) << 16);
}

__global__ void k_zero(int* __restrict__ p, int n) {
    int i = blockIdx.x * blockDim.x + threadIdx.x;
    if (i < n) p[i] = 0;
}

__global__ void k_count(const int* __restrict__ dst, int* __restrict__ deg) {
    int stride = gridDim.x * blockDim.x;
    for (int e = blockIdx.x * blockDim.x + threadIdx.x; e < N_EDGES; e += stride)
        atomicAdd(&deg[__builtin_nontemporal_load(&dst[e])], 1);
}

__global__ void k_scanA(const int* __restrict__ deg, int* __restrict__ row, int* __restrict__ bsum) {
    __shared__ int s[1024];
    int t = threadIdx.x;
    int gi = blockIdx.x * 1024 + t;
    s[t] = deg[gi];
    __syncthreads();
    for (int off = 1; off < 1024; off <<= 1) {
        int x = (t >= off) ? s[t - off] : 0;
        __syncthreads();
        s[t] += x;
        __syncthreads();
    }
    row[gi + 1] = s[t];
    if (t == 1023) bsum[blockIdx.x] = s[t];
}

__global__ void k_scanB(const int* __restrict__ bsum, int* __restrict__ boff) {
    __shared__ int s[84];
    int t = threadIdx.x;
    if (t < 84) s[t] = bsum[t];
    __syncthreads();
    if (t == 0) {
        int r = 0;
        for (int b = 0; b < 84; ++b) { int v = s[b]; s[b] = r; r += v; }
    }
    __syncthreads();
    if (t < 84) boff[t] = s[t];
}

__global__ void k_scanC(int* __restrict__ row, const int* __restrict__ boff) {
    int t = threadIdx.x;
    int gi = blockIdx.x * 1024 + t;
    row[gi + 1] += boff[blockIdx.x];
    if (gi == 0) row[0] = 0;
}

// Single-phase scatter, per-node cursors (86K counters -> low atomic contention).
// NT loads keep the streamed inputs out of L2 so write lines survive to merge.
__global__ void k_scatter(const int* __restrict__ ei, const float* __restrict__ ea,
                          const int* __restrict__ row, int* __restrict__ fill,
                          float4* __restrict__ rec) {
    int stride = gridDim.x * blockDim.x;
    for (int e = blockIdx.x * blockDim.x + threadIdx.x; e < N_EDGES; e += stride) {
        int s = __builtin_nontemporal_load(&ei[e]);
        int d = __builtin_nontemporal_load(&ei[N_EDGES + e]);
        float ax = __builtin_nontemporal_load(&ea[2 * e]);
        float ay = __builtin_nontemporal_load(&ea[2 * e + 1]);
        int pos = row[d] + atomicAdd(&fill[d], 1);
        float4 r;
        r.x = __int_as_float(s);
        r.y = ax;
        r.z = ay;
        r.w = 0.f;
        rec[pos] = r;
    }
}

// fold[l*2+c] = sum_j We[l][c][j] * att_edge[l][j]
__global__ void k_fold(const float* __restrict__ We, const float* __restrict__ ae,
                       float* __restrict__ fold) {
    int t = threadIdx.x;
    if (t < 8) {
        int l = t >> 1, c = t & 1;
        float s = 0.f;
        for (int j = 0; j < 32; ++j) s += We[l * 64 + c * 32 + j] * ae[l * 32 + j];
        fold[t] = s;
    }
}

__global__ void k_transform0(const float* __restrict__ x, const float* __restrict__ W0,
                             const float* __restrict__ as_w, const float* __restrict__ ad_w,
                             unsigned short* __restrict__ hout, float* __restrict__ as_arr,
                             float* __restrict__ ad_arr) {
    int tid = blockIdx.x * 256 + threadIdx.x;
    int j = tid & 31;
    int n = tid >> 5;
    float acc = x[n] * W0[j];
    hout[tid] = f2bf(acc);
    float v1 = acc * as_w[j], v2 = acc * ad_w[j];
#pragma unroll
    for (int m = 16; m >= 1; m >>= 1) {
        v1 += __shfl_xor(v1, m);
        v2 += __shfl_xor(v2, m);
    }
    if (j == 0) { as_arr[n] = v1; ad_arr[n] = v2; }
}

__global__ void k_transform(const float* __restrict__ hin, const float* __restrict__ W,
                            const float* __restrict__ as_w, const float* __restrict__ ad_w,
                            unsigned short* __restrict__ hout, float* __restrict__ as_arr,
                            float* __restrict__ ad_arr) {
    __shared__ float Wl[1024];
    int t = threadIdx.x;
#pragma unroll
    for (int i = 0; i < 4; ++i) Wl[t + i * 256] = W[t + i * 256];
    __syncthreads();
    int tid = blockIdx.x * 256 + t;
    int j = tid & 31;
    int n = tid >> 5;
    float hv = hin[tid];
    float acc = 0.f;
#pragma unroll
    for (int k = 0; k < 32; ++k) acc += __shfl(hv, k, 32) * Wl[k * 32 + j];
    hout[tid] = f2bf(acc);
    float v1 = acc * as_w[j], v2 = acc * ad_w[j];
#pragma unroll
    for (int m = 16; m >= 1; m >>= 1) {
        v1 += __shfl_xor(v1, m);
        v2 += __shfl_xor(v2, m);
    }
    if (j == 0) { as_arr[n] = v1; ad_arr[n] = v2; }
}

// one wave per node; lane&31 = feature dim; half-waves take alternating edges;
// 4-deep unroll. hT is bf16 (64 B/row -> half the random-touch traffic);
// rec stream read non-temporally (read-once; keep L2 for hT).
__global__ void k_gather(const unsigned short* __restrict__ hT, const float4* __restrict__ rec,
                         const int* __restrict__ row,
                         const float* __restrict__ as_arr, const float* __restrict__ ad_arr,
                         const float* __restrict__ fold, const float* __restrict__ bias,
                         float* __restrict__ out, int do_relu) {
    const nfloat4* nrec = (const nfloat4*)rec;
    int lane = threadIdx.x & 63;
    int n = blockIdx.x * 4 + (threadIdx.x >> 6);
    int j = lane & 31;
    int half = lane >> 5;
    int beg = row[n], end = row[n + 1];
    float c_dst = ad_arr[n];
    float f0 = fold[0], f1 = fold[1];
    float acc = 0.f, den = 0.f, esum = 0.f;
    int e = beg + half;
    for (; e + 6 < end; e += 8) {
        nfloat4 r0 = __builtin_nontemporal_load(&nrec[e]);
        nfloat4 r1 = __builtin_nontemporal_load(&nrec[e + 2]);
        nfloat4 r2 = __builtin_nontemporal_load(&nrec[e + 4]);
        nfloat4 r3 = __builtin_nontemporal_load(&nrec[e + 6]);
        int s0 = __float_as_int(r0.x);
        int s1 = __float_as_int(r1.x);
        int s2 = __float_as_int(r2.x);
        int s3 = __float_as_int(r3.x);
        float h0 = bf2f(hT[(s0 << 5) + j]);
        float h1 = bf2f(hT[(s1 << 5) + j]);
        float h2 = bf2f(hT[(s2 << 5) + j]);
        float h3 = bf2f(hT[(s3 << 5) + j]);
        float a0 = as_arr[s0];
        float a1 = as_arr[s1];
        float a2 = as_arr[s2];
        float a3 = as_arr[s3];
        float ed0 = r0.y * f0 + r0.z * f1;
        float ed1 = r1.y * f0 + r1.z * f1;
        float ed2 = r2.y * f0 + r2.z * f1;
        float ed3 = r3.y * f0 + r3.z * f1;
        float lg0 = a0 + c_dst + ed0; lg0 = fmaxf(lg0, NEG * lg0);
        float lg1 = a1 + c_dst + ed1; lg1 = fmaxf(lg1, NEG * lg1);
        float lg2 = a2 + c_dst + ed2; lg2 = fmaxf(lg2, NEG * lg2);
        float lg3 = a3 + c_dst + ed3; lg3 = fmaxf(lg3, NEG * lg3);
        float w0 = __expf(lg0);
        float w1 = __expf(lg1);
        float w2 = __expf(lg2);
        float w3 = __expf(lg3);
        den += (w0 + w1) + (w2 + w3);
        esum += (ed0 + ed1) + (ed2 + ed3);
        acc += w0 * h0;
        acc += w1 * h1;
        acc += w2 * h2;
        acc += w3 * h3;
    }
    for (; e < end; e += 2) {
        nfloat4 r = __builtin_nontemporal_load(&nrec[e]);
        int s = __float_as_int(r.x);
        float h = bf2f(hT[(s << 5) + j]);
        float ed = r.y * f0 + r.z * f1;
        float lg = as_arr[s] + c_dst + ed;
        lg = fmaxf(lg, NEG * lg);
        float w = __expf(lg);
        den += w;
        esum += ed;
        acc += w * h;
    }
    acc += __shfl_xor(acc, 32);
    den += __shfl_xor(den, 32);
    esum += __shfl_xor(esum, 32);
    // self loop: edge attr = mean of incoming (0 if deg==0), src = n
    int dg = end - beg;
    float el = esum / fmaxf((float)dg, 1.0f);
    float lg = as_arr[n] + c_dst + el;
    lg = fmaxf(lg, NEG * lg);
    float w = __expf(lg);
    den += w;
    acc += w * bf2f(hT[(n << 5) + j]);
    float o = acc / den + bias[j];
    if (do_relu) o = fmaxf(o, 0.f);
    if (half == 0) out[(n << 5) + j] = o;
}

__global__ void k_pool(const float* __restrict__ h, const float* __restrict__ lw,
                       const float* __restrict__ lb, float* __restrict__ out) {
    int lane = threadIdx.x & 63;
    int g = blockIdx.x * 4 + (threadIdx.x >> 6);
    int j = lane & 31;
    int half = lane >> 5;
    const float* base = h + (size_t)g * NPG * HID;
    float acc = 0.f;
    for (int i = half; i < NPG; i += 2) acc += base[i * HID + j];
    acc += __shfl_xor(acc, 32);
    float v = acc * lw[j];
#pragma unroll
    for (int m = 16; m >= 1; m >>= 1) v += __shfl_xor(v, m);
    if (lane == 0) out[g] = fmaxf(v + lb[0], 0.f);
}

extern "C" void kernel_launch(void* const* d_in, const int* in_sizes, int n_in,
                              void* d_out, int out_size, void* d_ws, size_t ws_size,
                              hipStream_t stream) {
    const float* x        = (const float*)d_in[0];
    const int*   ei       = (const int*)d_in[1];
    const float* eattr    = (const float*)d_in[2];
    const float* W0       = (const float*)d_in[3];
    const float* Ws       = (const float*)d_in[4];
    const float* att_src  = (const float*)d_in[5];
    const float* att_dst  = (const float*)d_in[6];
    const float* We       = (const float*)d_in[7];
    const float* att_edge = (const float*)d_in[8];
    const float* bias     = (const float*)d_in[9];
    const float* lin_w    = (const float*)d_in[10];
    const float* lin_b    = (const float*)d_in[11];
    float* out = (float*)d_out;

    char* w = (char*)d_ws;
    float4*         rec    = (float4*)(w + O_REC);
    unsigned short* hT     = (unsigned short*)(w + O_HT);
    float*          hB     = (float*)(w + O_HB);
    float*          as_arr = (float*)(w + O_AS);
    float*          ad_arr = (float*)(w + O_AD);
    int*            deg    = (int*)(w + O_DEG);
    int*            row    = (int*)(w + O_ROW);
    int*            fill   = (int*)(w + O_FILL);
    int*            bsum   = (int*)(w + O_BSUM);
    int*            boff   = (int*)(w + O_BOFF);
    float*          fold   = (float*)(w + O_FOLD);

    // ---- build CSR by dst ----
    k_zero<<<(2 * N_NODES + 255) / 256, 256, 0, stream>>>(deg, 2 * N_NODES);
    k_count<<<4096, 256, 0, stream>>>(ei + N_EDGES, deg);
    k_scanA<<<84, 1024, 0, stream>>>(deg, row, bsum);
    k_scanB<<<1, 128, 0, stream>>>(bsum, boff);
    k_scanC<<<84, 1024, 0, stream>>>(row, boff);
    k_scatter<<<8192, 256, 0, stream>>>(ei, eattr, row, fill, rec);
    k_fold<<<1, 64, 0, stream>>>(We, att_edge, fold);

    // ---- layer 0 ----
    k_transform0<<<N_NODES * HID / 256, 256, 0, stream>>>(x, W0, att_src, att_dst,
                                                          hT, as_arr, ad_arr);
    k_gather<<<N_NODES / 4, 256, 0, stream>>>(hT, rec, row, as_arr, ad_arr,
                                              fold, bias, hB, 1);
    // ---- layers 1..3 ----
    for (int l = 1; l < 4; ++l) {
        k_transform<<<N_NODES * HID / 256, 256, 0, stream>>>(
            hB, Ws + (size_t)(l - 1) * HID * HID, att_src + l * HID, att_dst + l * HID,
            hT, as_arr, ad_arr);
        k_gather<<<N_NODES / 4, 256, 0, stream>>>(hT, rec, row, as_arr, ad_arr,
                                                  fold + 2 * l, bias + l * HID, hB,
                                                  (l < 3) ? 1 : 0);
    }

    // ---- pool + linear + relu ----
    k_pool<<<B_GR / 4, 256, 0, stream>>>(hB, lin_w, lin_b, out);
}

// Round 6
// 1183.040 us; speedup vs baseline: 1.0800x; 1.0021x over previous
//
#include <hip/hip_runtime.h>

#define N_NODES 86016
#define N_EDGES 4194304
#define HID 32
#define B_GR 1024
#define NPG 84
#define NEG 0.2f

// ---- workspace layout (bytes) ----
// Edge record: float4 {src(int), ea.x, ea.y, unused}
// hT split into two half-dim arrays (N x 16 bf16 = 2.75 MB each) so one gather
// pass's random working set fits a 4 MiB per-XCD L2.
constexpr size_t O_REC  = 0;                                   // E * 16 B
constexpr size_t O_HTLO = O_REC  + (size_t)N_EDGES * 16;       // N*16 bf16
constexpr size_t O_HTHI = O_HTLO + (size_t)N_NODES * 16 * 2;   // N*16 bf16
constexpr size_t O_HB   = O_HTHI + (size_t)N_NODES * 16 * 2;   // N*32 f32
constexpr size_t O_AS   = O_HB  + (size_t)N_NODES * HID * 4;   // N f32
constexpr size_t O_AD   = O_AS  + (size_t)N_NODES * 4;         // N f32
constexpr size_t O_DEG  = O_AD  + (size_t)N_NODES * 4;         // N int
constexpr size_t O_FILL = O_DEG + (size_t)N_NODES * 4;         // N int
constexpr size_t O_ROW  = O_FILL + (size_t)N_NODES * 4;        // N+1 int
constexpr size_t O_BSUM = O_ROW + (size_t)(N_NODES + 1) * 4 + 12; // 84 int
constexpr size_t O_BOFF = O_BSUM + 84 * 4;                     // 84 int
constexpr size_t O_FOLD = O_BOFF + 84 * 4;                     // 8 f32

__device__ __forceinline__ unsigned short f2bf(float f) {
    unsigned u = __float_as_uint(f);
    u += 0x7FFFu + ((u >> 16) & 1u);      // round-to-nearest-even
    return (unsigned short)(u >> 16);
}
__device__ __forceinline__ float bf2f(unsigned short b) {
    return __uint_as_float(((unsigned)b) << 16);
}

__global__ void k_zero(int* __restrict__ p, int n) {
    int i = blockIdx.x * blockDim.x + threadIdx.x;
    if (i < n) p[i] = 0;
}

__global__ void k_count(const int* __restrict__ dst, int* __restrict__ deg) {
    int stride = gridDim.x * blockDim.x;
    for (int e = blockIdx.x * blockDim.x + threadIdx.x; e < N_EDGES; e += stride)
        atomicAdd(&deg[dst[e]], 1);
}

__global__ void k_scanA(const int* __restrict__ deg, int* __restrict__ row, int* __restrict__ bsum) {
    __shared__ int s[1024];
    int t = threadIdx.x;
    int gi = blockIdx.x * 1024 + t;
    s[t] = deg[gi];
    __syncthreads();
    for (int off = 1; off < 1024; off <<= 1) {
        int x = (t >= off) ? s[t - off] : 0;
        __syncthreads();
        s[t] += x;
        __syncthreads();
    }
    row[gi + 1] = s[t];
    if (t == 1023) bsum[blockIdx.x] = s[t];
}

__global__ void k_scanB(const int* __restrict__ bsum, int* __restrict__ boff) {
    __shared__ int s[84];
    int t = threadIdx.x;
    if (t < 84) s[t] = bsum[t];
    __syncthreads();
    if (t == 0) {
        int r = 0;
        for (int b = 0; b < 84; ++b) { int v = s[b]; s[b] = r; r += v; }
    }
    __syncthreads();
    if (t < 84) boff[t] = s[t];
}

__global__ void k_scanC(int* __restrict__ row, const int* __restrict__ boff) {
    int t = threadIdx.x;
    int gi = blockIdx.x * 1024 + t;
    row[gi + 1] += boff[blockIdx.x];
    if (gi == 0) row[0] = 0;
}

// Single-phase scatter, per-node cursors (86K counters -> low atomic contention).
__global__ void k_scatter(const int* __restrict__ ei, const float2* __restrict__ ea,
                          const int* __restrict__ row, int* __restrict__ fill,
                          float4* __restrict__ rec) {
    int stride = gridDim.x * blockDim.x;
    for (int e = blockIdx.x * blockDim.x + threadIdx.x; e < N_EDGES; e += stride) {
        int s = ei[e];
        int d = ei[N_EDGES + e];
        float2 a = ea[e];
        int pos = row[d] + atomicAdd(&fill[d], 1);
        float4 r;
        r.x = __int_as_float(s);
        r.y = a.x;
        r.z = a.y;
        r.w = 0.f;
        rec[pos] = r;
    }
}

// fold[l*2+c] = sum_j We[l][c][j] * att_edge[l][j]
__global__ void k_fold(const float* __restrict__ We, const float* __restrict__ ae,
                       float* __restrict__ fold) {
    int t = threadIdx.x;
    if (t < 8) {
        int l = t >> 1, c = t & 1;
        float s = 0.f;
        for (int j = 0; j < 32; ++j) s += We[l * 64 + c * 32 + j] * ae[l * 32 + j];
        fold[t] = s;
    }
}

__global__ void k_transform0(const float* __restrict__ x, const float* __restrict__ W0,
                             const float* __restrict__ as_w, const float* __restrict__ ad_w,
                             unsigned short* __restrict__ hlo, unsigned short* __restrict__ hhi,
                             float* __restrict__ as_arr, float* __restrict__ ad_arr) {
    int tid = blockIdx.x * 256 + threadIdx.x;
    int j = tid & 31;
    int n = tid >> 5;
    float acc = x[n] * W0[j];
    unsigned short* hdst = (j < 16) ? hlo : hhi;
    hdst[(n << 4) + (j & 15)] = f2bf(acc);
    float v1 = acc * as_w[j], v2 = acc * ad_w[j];
#pragma unroll
    for (int m = 16; m >= 1; m >>= 1) {
        v1 += __shfl_xor(v1, m);
        v2 += __shfl_xor(v2, m);
    }
    if (j == 0) { as_arr[n] = v1; ad_arr[n] = v2; }
}

__global__ void k_transform(const float* __restrict__ hin, const float* __restrict__ W,
                            const float* __restrict__ as_w, const float* __restrict__ ad_w,
                            unsigned short* __restrict__ hlo, unsigned short* __restrict__ hhi,
                            float* __restrict__ as_arr, float* __restrict__ ad_arr) {
    __shared__ float Wl[1024];
    int t = threadIdx.x;
#pragma unroll
    for (int i = 0; i < 4; ++i) Wl[t + i * 256] = W[t + i * 256];
    __syncthreads();
    int tid = blockIdx.x * 256 + t;
    int j = tid & 31;
    int n = tid >> 5;
    float hv = hin[tid];
    float acc = 0.f;
#pragma unroll
    for (int k = 0; k < 32; ++k) acc += __shfl(hv, k, 32) * Wl[k * 32 + j];
    unsigned short* hdst = (j < 16) ? hlo : hhi;
    hdst[(n << 4) + (j & 15)] = f2bf(acc);
    float v1 = acc * as_w[j], v2 = acc * ad_w[j];
#pragma unroll
    for (int m = 16; m >= 1; m >>= 1) {
        v1 += __shfl_xor(v1, m);
        v2 += __shfl_xor(v2, m);
    }
    if (j == 0) { as_arr[n] = v1; ad_arr[n] = v2; }
}

// One wave per node, HALF the feature dims per pass: 64 lanes = 4 edge slots
// (quarter-waves) x 16 dims. hhalf is a 2.75 MB array -> fits per-XCD L2, so
// the random row touches stay L2-resident. Attention recomputed per pass.
__global__ void k_gather_half(const unsigned short* __restrict__ hhalf,
                              const float4* __restrict__ rec, const int* __restrict__ row,
                              const float* __restrict__ as_arr, const float* __restrict__ ad_arr,
                              const float* __restrict__ fold, const float* __restrict__ bias,
                              float* __restrict__ out, int halfsel, int do_relu) {
    int lane = threadIdx.x & 63;
    int n = blockIdx.x * 4 + (threadIdx.x >> 6);
    int j = lane & 15;
    int q = lane >> 4;           // edge slot 0..3
    int beg = row[n], end = row[n + 1];
    float c_dst = ad_arr[n];
    float f0 = fold[0], f1 = fold[1];
    float acc = 0.f, den = 0.f, esum = 0.f;
    int e = beg + q;
    for (; e + 4 < end; e += 8) {
        float4 r0 = rec[e];
        float4 r1 = rec[e + 4];
        int s0 = __float_as_int(r0.x);
        int s1 = __float_as_int(r1.x);
        float h0 = bf2f(hhalf[(s0 << 4) + j]);
        float h1 = bf2f(hhalf[(s1 << 4) + j]);
        float a0 = as_arr[s0];
        float a1 = as_arr[s1];
        float ed0 = r0.y * f0 + r0.z * f1;
        float ed1 = r1.y * f0 + r1.z * f1;
        float lg0 = a0 + c_dst + ed0; lg0 = fmaxf(lg0, NEG * lg0);
        float lg1 = a1 + c_dst + ed1; lg1 = fmaxf(lg1, NEG * lg1);
        float w0 = __expf(lg0);
        float w1 = __expf(lg1);
        den += w0 + w1;
        esum += ed0 + ed1;
        acc += w0 * h0;
        acc += w1 * h1;
    }
    for (; e < end; e += 4) {
        float4 r = rec[e];
        int s = __float_as_int(r.x);
        float h = bf2f(hhalf[(s << 4) + j]);
        float ed = r.y * f0 + r.z * f1;
        float lg = as_arr[s] + c_dst + ed;
        lg = fmaxf(lg, NEG * lg);
        float w = __expf(lg);
        den += w;
        esum += ed;
        acc += w * h;
    }
    // reduce across the 4 quarter-waves
    acc += __shfl_xor(acc, 16);
    acc += __shfl_xor(acc, 32);
    den += __shfl_xor(den, 16);
    den += __shfl_xor(den, 32);
    esum += __shfl_xor(esum, 16);
    esum += __shfl_xor(esum, 32);
    // self loop: edge attr = mean of incoming (0 if deg==0), src = n
    int dg = end - beg;
    float el = esum / fmaxf((float)dg, 1.0f);
    float lg = as_arr[n] + c_dst + el;
    lg = fmaxf(lg, NEG * lg);
    float w = __expf(lg);
    den += w;
    acc += w * bf2f(hhalf[(n << 4) + j]);
    float o = acc / den + bias[(halfsel << 4) + j];
    if (do_relu) o = fmaxf(o, 0.f);
    if (lane < 16) out[(n << 5) + (halfsel << 4) + j] = o;
}

__global__ void k_pool(const float* __restrict__ h, const float* __restrict__ lw,
                       const float* __restrict__ lb, float* __restrict__ out) {
    int lane = threadIdx.x & 63;
    int g = blockIdx.x * 4 + (threadIdx.x >> 6);
    int j = lane & 31;
    int half = lane >> 5;
    const float* base = h + (size_t)g * NPG * HID;
    float acc = 0.f;
    for (int i = half; i < NPG; i += 2) acc += base[i * HID + j];
    acc += __shfl_xor(acc, 32);
    float v = acc * lw[j];
#pragma unroll
    for (int m = 16; m >= 1; m >>= 1) v += __shfl_xor(v, m);
    if (lane == 0) out[g] = fmaxf(v + lb[0], 0.f);
}

extern "C" void kernel_launch(void* const* d_in, const int* in_sizes, int n_in,
                              void* d_out, int out_size, void* d_ws, size_t ws_size,
                              hipStream_t stream) {
    const float* x        = (const float*)d_in[0];
    const int*   ei       = (const int*)d_in[1];
    const float* eattr    = (const float*)d_in[2];
    const float* W0       = (const float*)d_in[3];
    const float* Ws       = (const float*)d_in[4];
    const float* att_src  = (const float*)d_in[5];
    const float* att_dst  = (const float*)d_in[6];
    const float* We       = (const float*)d_in[7];
    const float* att_edge = (const float*)d_in[8];
    const float* bias     = (const float*)d_in[9];
    const float* lin_w    = (const float*)d_in[10];
    const float* lin_b    = (const float*)d_in[11];
    float* out = (float*)d_out;

    char* w = (char*)d_ws;
    float4*         rec    = (float4*)(w + O_REC);
    unsigned short* hlo    = (unsigned short*)(w + O_HTLO);
    unsigned short* hhi    = (unsigned short*)(w + O_HTHI);
    float*          hB     = (float*)(w + O_HB);
    float*          as_arr = (float*)(w + O_AS);
    float*          ad_arr = (float*)(w + O_AD);
    int*            deg    = (int*)(w + O_DEG);
    int*            row    = (int*)(w + O_ROW);
    int*            fill   = (int*)(w + O_FILL);
    int*            bsum   = (int*)(w + O_BSUM);
    int*            boff   = (int*)(w + O_BOFF);
    float*          fold   = (float*)(w + O_FOLD);

    // ---- build CSR by dst ----
    k_zero<<<(2 * N_NODES + 255) / 256, 256, 0, stream>>>(deg, 2 * N_NODES);
    k_count<<<4096, 256, 0, stream>>>(ei + N_EDGES, deg);
    k_scanA<<<84, 1024, 0, stream>>>(deg, row, bsum);
    k_scanB<<<1, 128, 0, stream>>>(bsum, boff);
    k_scanC<<<84, 1024, 0, stream>>>(row, boff);
    k_scatter<<<8192, 256, 0, stream>>>(ei, (const float2*)eattr, row, fill, rec);
    k_fold<<<1, 64, 0, stream>>>(We, att_edge, fold);

    // ---- layer 0 ----
    k_transform0<<<N_NODES * HID / 256, 256, 0, stream>>>(x, W0, att_src, att_dst,
                                                          hlo, hhi, as_arr, ad_arr);
    k_gather_half<<<N_NODES / 4, 256, 0, stream>>>(hlo, rec, row, as_arr, ad_arr,
                                                   fold, bias, hB, 0, 1);
    k_gather_half<<<N_NODES / 4, 256, 0, stream>>>(hhi, rec, row, as_arr, ad_arr,
                                                   fold, bias, hB, 1, 1);
    // ---- layers 1..3 ----
    for (int l = 1; l < 4; ++l) {
        k_transform<<<N_NODES * HID / 256, 256, 0, stream>>>(
            hB, Ws + (size_t)(l - 1) * HID * HID, att_src + l * HID, att_dst + l * HID,
            hlo, hhi, as_arr, ad_arr);
        int dr = (l < 3) ? 1 : 0;
        k_gather_half<<<N_NODES / 4, 256, 0, stream>>>(hlo, rec, row, as_arr, ad_arr,
                                                       fold + 2 * l, bias + l * HID, hB, 0, dr);
        k_gather_half<<<N_NODES / 4, 256, 0, stream>>>(hhi, rec, row, as_arr, ad_arr,
                                                       fold + 2 * l, bias + l * HID, hB, 1, dr);
    }

    // ---- pool + linear + relu ----
    k_pool<<<B_GR / 4, 256, 0, stream>>>(hB, lin_w, lin_b, out);
}

// Round 7
// 602.728 us; speedup vs baseline: 2.1198x; 1.9628x over previous
//
#include <hip/hip_runtime.h>

#define N_NODES 86016
#define N_EDGES 4194304
#define HID 32
#define B_GR 1024
#define NPG 84
#define NEG 0.2f

#define NCH 2048      // chunks (edges are processed in NCH chunks of CHE)
#define CHE 2048      // edges per chunk; NCH*CHE == N_EDGES
#define NB  512       // dst buckets
#define NPB 168       // nodes per bucket; NB*NPB == N_NODES

// ---- workspace layout (bytes) ----
constexpr size_t O_REC   = 0;                                    // E * 16
constexpr size_t O_CM    = O_REC  + (size_t)N_EDGES * 16;        // NB*NCH int (chunk matrix)
constexpr size_t O_HT    = O_CM   + (size_t)NB * NCH * 4;        // N*32 bf16
constexpr size_t O_HB    = O_HT   + (size_t)N_NODES * HID * 2;   // N*32 f32
constexpr size_t O_AS    = O_HB   + (size_t)N_NODES * HID * 4;   // N f32
constexpr size_t O_AD    = O_AS   + (size_t)N_NODES * 4;         // N f32
constexpr size_t O_ROW   = O_AD   + (size_t)N_NODES * 4;         // N+1 int
constexpr size_t O_BTOT  = O_ROW  + (size_t)(N_NODES + 1) * 4 + 12; // NB int (16B aligned)
constexpr size_t O_BBASE = O_BTOT + (size_t)NB * 4;              // NB+1 int
constexpr size_t O_FOLD  = O_BBASE + (size_t)(NB + 1) * 4 + 12;  // 8 f32

__device__ __forceinline__ unsigned short f2bf(float f) {
    unsigned u = __float_as_uint(f);
    u += 0x7FFFu + ((u >> 16) & 1u);      // round-to-nearest-even
    return (unsigned short)(u >> 16);
}
__device__ __forceinline__ float bf2f(unsigned short b) {
    return __uint_as_float(((unsigned)b) << 16);
}

// ---- CSR build, atomic-free ----
// 1) per-chunk per-bucket histogram -> cm[bucket][chunk]
__global__ void k_hist(const int* __restrict__ dst, int* __restrict__ cm) {
    __shared__ int cnt[NB];
    int t = threadIdx.x, c = blockIdx.x;
    cnt[t] = 0; cnt[t + 256] = 0;
    __syncthreads();
    int base = c * CHE;
#pragma unroll
    for (int k = 0; k < 8; ++k) {
        int d = dst[base + k * 256 + t];
        atomicAdd(&cnt[(unsigned)d / NPB], 1);
    }
    __syncthreads();
    cm[t * NCH + c] = cnt[t];
    cm[(t + 256) * NCH + c] = cnt[t + 256];
}

// 2) per-bucket exclusive scan over chunks (in place); bucket totals out
__global__ __launch_bounds__(1024) void k_scanchunks(int* __restrict__ cm, int* __restrict__ btot) {
    __shared__ int sa[NCH], sb[NCH];
    int b = blockIdx.x, t = threadIdx.x;
    sa[t] = cm[b * NCH + t];
    sa[t + 1024] = cm[b * NCH + t + 1024];
    __syncthreads();
    int* s = sa; int* d = sb;
    for (int off = 1; off < NCH; off <<= 1) {
        for (int i = t; i < NCH; i += 1024)
            d[i] = s[i] + (i >= off ? s[i - off] : 0);
        __syncthreads();
        int* tmp = s; s = d; d = tmp;
    }
    // s = inclusive scan
    cm[b * NCH + t] = t ? s[t - 1] : 0;
    cm[b * NCH + t + 1024] = s[t + 1023];
    if (t == 0) btot[b] = s[NCH - 1];
}

// 3) exclusive scan of bucket totals -> bbase[NB+1]; also row[N]=E
__global__ void k_scanbuckets(const int* __restrict__ btot, int* __restrict__ bbase,
                              int* __restrict__ row) {
    __shared__ int sa[NB], sb[NB];
    int t = threadIdx.x;
    sa[t] = btot[t];
    __syncthreads();
    int* s = sa; int* d = sb;
    for (int off = 1; off < NB; off <<= 1) {
        d[t] = s[t] + (t >= off ? s[t - off] : 0);
        __syncthreads();
        int* tmp = s; s = d; d = tmp;
    }
    bbase[t] = t ? s[t - 1] : 0;
    if (t == NB - 1) { bbase[NB] = s[NB - 1]; row[N_NODES] = s[NB - 1]; }
}

// 4) place edge records into bucket regions; writes are runs of ~4 recs per
//    (chunk,bucket) -> full 64B sectors. No global atomics.
__global__ void k_place(const int* __restrict__ ei, const float2* __restrict__ ea,
                        const int* __restrict__ cm, const int* __restrict__ bbase,
                        float4* __restrict__ rec) {
    __shared__ int cnt[NB];
    __shared__ int base[NB];
    int t = threadIdx.x, c = blockIdx.x;
    cnt[t] = 0; cnt[t + 256] = 0;
    __syncthreads();
    int eb = c * CHE;
    int bin[8], rnk[8], srcv[8], dstv[8];
    float2 eav[8];
#pragma unroll
    for (int k = 0; k < 8; ++k) {
        int e = eb + k * 256 + t;
        srcv[k] = ei[e];
        dstv[k] = ei[N_EDGES + e];
        eav[k] = ea[e];
        bin[k] = (unsigned)dstv[k] / NPB;
        rnk[k] = atomicAdd(&cnt[bin[k]], 1);
    }
    __syncthreads();
    base[t] = bbase[t] + cm[t * NCH + c];
    base[t + 256] = bbase[t + 256] + cm[(t + 256) * NCH + c];
    __syncthreads();
#pragma unroll
    for (int k = 0; k < 8; ++k) {
        float4 r;
        r.x = __int_as_float(srcv[k]);
        r.y = eav[k].x;
        r.z = eav[k].y;
        r.w = __int_as_float(dstv[k]);
        rec[base[bin[k]] + rnk[k]] = r;
    }
}

// 5) per-bucket sort to node order (records staged in registers; scattered
//    16B writes confined to a 131 KB window -> L2-merged). Also emits row[].
__global__ __launch_bounds__(1024) void k_sort(float4* __restrict__ rec,
                                               const int* __restrict__ bbase,
                                               int* __restrict__ row) {
    __shared__ int cnt[256], tmp[256], ebase[256], fill[256];
    int b = blockIdx.x, t = threadIdx.x;
    int n0 = b * NPB;
    int beg = bbase[b], end = bbase[b + 1], m = end - beg;
    if (t < 256) { cnt[t] = 0; fill[t] = 0; }
    __syncthreads();
    float4 rv[12];
    int cv = 0;
    for (int i = t; i < m; i += 1024) {
        float4 r = rec[beg + i];
        if (cv < 12) rv[cv] = r;
        cv++;
        atomicAdd(&cnt[__float_as_int(r.w) - n0], 1);
    }
    __syncthreads();
    // exclusive scan of cnt[256] -> ebase
    int* s = cnt; int* d = tmp;
    for (int off = 1; off < 256; off <<= 1) {
        int v = 0;
        if (t < 256) v = s[t] + (t >= off ? s[t - off] : 0);
        __syncthreads();
        if (t < 256) d[t] = v;
        __syncthreads();
        int* tp = s; s = d; d = tp;
    }
    if (t < 256) ebase[t] = t ? s[t - 1] : 0;
    __syncthreads();
    if (t < NPB) row[n0 + t] = beg + ebase[t];
    int idx = 0;
    for (int i = t; i < m; i += 1024) {
        float4 r = (idx < 12) ? rv[idx] : rec[beg + i];  // reread only on >12288-edge bucket (~0 prob)
        idx++;
        int dn = __float_as_int(r.w) - n0;
        int p = atomicAdd(&fill[dn], 1);
        rec[beg + ebase[dn] + p] = r;
    }
}

// fold[l*2+c] = sum_j We[l][c][j] * att_edge[l][j]
__global__ void k_fold(const float* __restrict__ We, const float* __restrict__ ae,
                       float* __restrict__ fold) {
    int t = threadIdx.x;
    if (t < 8) {
        int l = t >> 1, c = t & 1;
        float s = 0.f;
        for (int j = 0; j < 32; ++j) s += We[l * 64 + c * 32 + j] * ae[l * 32 + j];
        fold[t] = s;
    }
}

__global__ void k_transform0(const float* __restrict__ x, const float* __restrict__ W0,
                             const float* __restrict__ as_w, const float* __restrict__ ad_w,
                             unsigned short* __restrict__ hout, float* __restrict__ as_arr,
                             float* __restrict__ ad_arr) {
    int tid = blockIdx.x * 256 + threadIdx.x;
    int j = tid & 31;
    int n = tid >> 5;
    float acc = x[n] * W0[j];
    hout[tid] = f2bf(acc);
    float v1 = acc * as_w[j], v2 = acc * ad_w[j];
#pragma unroll
    for (int m = 16; m >= 1; m >>= 1) {
        v1 += __shfl_xor(v1, m);
        v2 += __shfl_xor(v2, m);
    }
    if (j == 0) { as_arr[n] = v1; ad_arr[n] = v2; }
}

__global__ void k_transform(const float* __restrict__ hin, const float* __restrict__ W,
                            const float* __restrict__ as_w, const float* __restrict__ ad_w,
                            unsigned short* __restrict__ hout, float* __restrict__ as_arr,
                            float* __restrict__ ad_arr) {
    __shared__ float Wl[1024];
    int t = threadIdx.x;
#pragma unroll
    for (int i = 0; i < 4; ++i) Wl[t + i * 256] = W[t + i * 256];
    __syncthreads();
    int tid = blockIdx.x * 256 + t;
    int j = tid & 31;
    int n = tid >> 5;
    float hv = hin[tid];
    float acc = 0.f;
#pragma unroll
    for (int k = 0; k < 32; ++k) acc += __shfl(hv, k, 32) * Wl[k * 32 + j];
    hout[tid] = f2bf(acc);
    float v1 = acc * as_w[j], v2 = acc * ad_w[j];
#pragma unroll
    for (int m = 16; m >= 1; m >>= 1) {
        v1 += __shfl_xor(v1, m);
        v2 += __shfl_xor(v2, m);
    }
    if (j == 0) { as_arr[n] = v1; ad_arr[n] = v2; }
}

// One wave per node: 8 edge slots x 8 dim-lanes (4 dims each via ushort4).
// Each scalar VALU inst (logit/exp) serves 8 edges; bf16 row = 1 line/edge;
// rec wave-inst covers 128 B contiguous.
__global__ void k_gather(const unsigned short* __restrict__ hT, const float4* __restrict__ rec,
                         const int* __restrict__ row,
                         const float* __restrict__ as_arr, const float* __restrict__ ad_arr,
                         const float* __restrict__ fold, const float* __restrict__ bias,
                         float* __restrict__ out, int do_relu) {
    const ushort4* hv = (const ushort4*)hT;   // row n = hv[n*8 + dl]
    int lane = threadIdx.x & 63;
    int n = blockIdx.x * 4 + (threadIdx.x >> 6);
    int slot = lane >> 3;
    int dl = lane & 7;
    int beg = row[n], end = row[n + 1];
    float c_dst = ad_arr[n];
    float f0 = fold[0], f1 = fold[1];
    float4 acc = {0.f, 0.f, 0.f, 0.f};
    float den = 0.f, esum = 0.f;
    int e = beg;
    for (; e + 16 <= end; e += 16) {
        float4 r0 = rec[e + slot];
        float4 r1 = rec[e + 8 + slot];
        int s0 = __float_as_int(r0.x);
        int s1 = __float_as_int(r1.x);
        ushort4 h0 = hv[(s0 << 3) + dl];
        ushort4 h1 = hv[(s1 << 3) + dl];
        float a0 = as_arr[s0];
        float a1 = as_arr[s1];
        float ed0 = r0.y * f0 + r0.z * f1;
        float ed1 = r1.y * f0 + r1.z * f1;
        float lg0 = a0 + c_dst + ed0; lg0 = fmaxf(lg0, NEG * lg0);
        float lg1 = a1 + c_dst + ed1; lg1 = fmaxf(lg1, NEG * lg1);
        float w0 = __expf(lg0);
        float w1 = __expf(lg1);
        den += w0 + w1;
        esum += ed0 + ed1;
        acc.x += w0 * bf2f(h0.x) + w1 * bf2f(h1.x);
        acc.y += w0 * bf2f(h0.y) + w1 * bf2f(h1.y);
        acc.z += w0 * bf2f(h0.z) + w1 * bf2f(h1.z);
        acc.w += w0 * bf2f(h0.w) + w1 * bf2f(h1.w);
    }
    // tail (< 16 edges), slot-predicated
#pragma unroll
    for (int u = 0; u < 2; ++u) {
        int ee = e + 8 * u + slot;
        if (ee < end) {
            float4 r = rec[ee];
            int s = __float_as_int(r.x);
            ushort4 h = hv[(s << 3) + dl];
            float ed = r.y * f0 + r.z * f1;
            float lg = as_arr[s] + c_dst + ed;
            lg = fmaxf(lg, NEG * lg);
            float w = __expf(lg);
            den += w;
            esum += ed;
            acc.x += w * bf2f(h.x);
            acc.y += w * bf2f(h.y);
            acc.z += w * bf2f(h.z);
            acc.w += w * bf2f(h.w);
        }
    }
    // reduce across the 8 slots (xor 8,16,32 keeps dl)
#pragma unroll
    for (int m = 8; m <= 32; m <<= 1) {
        acc.x += __shfl_xor(acc.x, m);
        acc.y += __shfl_xor(acc.y, m);
        acc.z += __shfl_xor(acc.z, m);
        acc.w += __shfl_xor(acc.w, m);
        den += __shfl_xor(den, m);
        esum += __shfl_xor(esum, m);
    }
    // self loop (every lane adds once post-reduction; only slot 0 writes)
    int dg = end - beg;
    float el = esum / fmaxf((float)dg, 1.0f);
    float lg = as_arr[n] + c_dst + el;
    lg = fmaxf(lg, NEG * lg);
    float w = __expf(lg);
    den += w;
    ushort4 hs = hv[(n << 3) + dl];
    acc.x += w * bf2f(hs.x);
    acc.y += w * bf2f(hs.y);
    acc.z += w * bf2f(hs.z);
    acc.w += w * bf2f(hs.w);
    float4 bv = *(const float4*)(bias + 4 * dl);
    float4 o;
    o.x = acc.x / den + bv.x;
    o.y = acc.y / den + bv.y;
    o.z = acc.z / den + bv.z;
    o.w = acc.w / den + bv.w;
    if (do_relu) {
        o.x = fmaxf(o.x, 0.f); o.y = fmaxf(o.y, 0.f);
        o.z = fmaxf(o.z, 0.f); o.w = fmaxf(o.w, 0.f);
    }
    if (slot == 0) *(float4*)(out + (n << 5) + 4 * dl) = o;
}

__global__ void k_pool(const float* __restrict__ h, const float* __restrict__ lw,
                       const float* __restrict__ lb, float* __restrict__ out) {
    int lane = threadIdx.x & 63;
    int g = blockIdx.x * 4 + (threadIdx.x >> 6);
    int j = lane & 31;
    int half = lane >> 5;
    const float* base = h + (size_t)g * NPG * HID;
    float acc = 0.f;
    for (int i = half; i < NPG; i += 2) acc += base[i * HID + j];
    acc += __shfl_xor(acc, 32);
    float v = acc * lw[j];
#pragma unroll
    for (int m = 16; m >= 1; m >>= 1) v += __shfl_xor(v, m);
    if (lane == 0) out[g] = fmaxf(v + lb[0], 0.f);
}

extern "C" void kernel_launch(void* const* d_in, const int* in_sizes, int n_in,
                              void* d_out, int out_size, void* d_ws, size_t ws_size,
                              hipStream_t stream) {
    const float* x        = (const float*)d_in[0];
    const int*   ei       = (const int*)d_in[1];
    const float* eattr    = (const float*)d_in[2];
    const float* W0       = (const float*)d_in[3];
    const float* Ws       = (const float*)d_in[4];
    const float* att_src  = (const float*)d_in[5];
    const float* att_dst  = (const float*)d_in[6];
    const float* We       = (const float*)d_in[7];
    const float* att_edge = (const float*)d_in[8];
    const float* bias     = (const float*)d_in[9];
    const float* lin_w    = (const float*)d_in[10];
    const float* lin_b    = (const float*)d_in[11];
    float* out = (float*)d_out;

    char* w = (char*)d_ws;
    float4*         rec    = (float4*)(w + O_REC);
    int*            cm     = (int*)(w + O_CM);
    unsigned short* hT     = (unsigned short*)(w + O_HT);
    float*          hB     = (float*)(w + O_HB);
    float*          as_arr = (float*)(w + O_AS);
    float*          ad_arr = (float*)(w + O_AD);
    int*            row    = (int*)(w + O_ROW);
    int*            btot   = (int*)(w + O_BTOT);
    int*            bbase  = (int*)(w + O_BBASE);
    float*          fold   = (float*)(w + O_FOLD);

    // ---- CSR build (atomic-free, write-clustered) ----
    k_hist<<<NCH, 256, 0, stream>>>(ei + N_EDGES, cm);
    k_scanchunks<<<NB, 1024, 0, stream>>>(cm, btot);
    k_scanbuckets<<<1, NB, 0, stream>>>(btot, bbase, row);
    k_place<<<NCH, 256, 0, stream>>>(ei, (const float2*)eattr, cm, bbase, rec);
    k_sort<<<NB, 1024, 0, stream>>>(rec, bbase, row);
    k_fold<<<1, 64, 0, stream>>>(We, att_edge, fold);

    // ---- layer 0 ----
    k_transform0<<<N_NODES * HID / 256, 256, 0, stream>>>(x, W0, att_src, att_dst,
                                                          hT, as_arr, ad_arr);
    k_gather<<<N_NODES / 4, 256, 0, stream>>>(hT, rec, row, as_arr, ad_arr,
                                              fold, bias, hB, 1);
    // ---- layers 1..3 ----
    for (int l = 1; l < 4; ++l) {
        k_transform<<<N_NODES * HID / 256, 256, 0, stream>>>(
            hB, Ws + (size_t)(l - 1) * HID * HID, att_src + l * HID, att_dst + l * HID,
            hT, as_arr, ad_arr);
        k_gather<<<N_NODES / 4, 256, 0, stream>>>(hT, rec, row, as_arr, ad_arr,
                                                  fold + 2 * l, bias + l * HID, hB,
                                                  (l < 3) ? 1 : 0);
    }

    // ---- pool + linear + relu ----
    k_pool<<<B_GR / 4, 256, 0, stream>>>(hB, lin_w, lin_b, out);
}